// Round 11
// baseline (89.020 us; speedup 1.0000x reference)
//
#include <hip/hip_runtime.h>
#include <math.h>

constexpr int NQ  = 12;
constexpr int NS  = 1 << NQ;   // 4096 amplitudes
constexpr int NL  = 4;
constexpr int BLK = 256;
constexpr int R   = 16;        // amplitudes per thread (reg bits = amp bits 0..3)
constexpr float PI_F = 3.14159265358979323846f;

// amp index i = (tid << 4) | r
//   bits 0..3  : register index r
//   bits 4..9  : lane bits (tid bits 0..5)
//   bits 10..11: wave bits (tid bits 6..7)

typedef float c32 __attribute__((ext_vector_type(2)));   // (re, im) -> v_pk_* math

__device__ __forceinline__ c32 cmul(c32 a, c32 b) {
    c32 t = (c32){-a.y, a.y} * b.yx;
    return (c32){a.x, a.x} * b + t;
}
struct cg { c32 xx, ny; };
__device__ __forceinline__ cg mkg(c32 u) {
    cg g; g.xx = (c32){u.x, u.x}; g.ny = (c32){-u.y, u.y}; return g;
}
__device__ __forceinline__ c32 cmulg(cg g, c32 b) { return g.xx * b + g.ny * b.yx; }
__device__ __forceinline__ c32 cmadg(cg g, c32 b, c32 c) { return g.xx * b + (g.ny * b.yx + c); }

// ---------------- VALU lane-exchange primitives ----------------
// row_shr:N = lane i <- i-N, row_shl:N = lane i <- i+N (verified R5).
template<int CTRL>
__device__ __forceinline__ float dppmov(float v) {
    return __int_as_float(__builtin_amdgcn_mov_dpp(__float_as_int(v), CTRL, 0xF, 0xF, false));
}
__device__ __forceinline__ float dppx4(float v) {
    int s = __float_as_int(v);
    int o = __builtin_amdgcn_update_dpp(s, s, 0x104, 0xF, 0x5, false); // row_shl:4 -> banks 0,2
    o     = __builtin_amdgcn_update_dpp(o, s, 0x114, 0xF, 0xA, false); // row_shr:4 -> banks 1,3
    return __int_as_float(o);
}

#if __has_builtin(__builtin_amdgcn_permlane16_swap)
#define HAVE_PL16 1
#endif
#if __has_builtin(__builtin_amdgcn_permlane32_swap)
#define HAVE_PL32 1
#endif

template<int M>
__device__ __forceinline__ float lanex(float v, int tid) {
    if constexpr (M == 1)  return dppmov<0xB1>(v);        // quad_perm [1,0,3,2]
    else if constexpr (M == 2)  return dppmov<0x4E>(v);   // quad_perm [2,3,0,1]
    else if constexpr (M == 4)  return dppx4(v);
    else if constexpr (M == 8)  return dppmov<0x128>(v);  // row_ror:8
    else if constexpr (M == 16) {
#ifdef HAVE_PL16
        auto r = __builtin_amdgcn_permlane16_swap(__float_as_int(v), __float_as_int(v), false, false);
        return __int_as_float((tid & 16) ? r[0] : r[1]);
#else
        return __shfl_xor(v, 16, 64);
#endif
    } else { // M == 32
#ifdef HAVE_PL32
        auto r = __builtin_amdgcn_permlane32_swap(__float_as_int(v), __float_as_int(v), false, false);
        return __int_as_float((tid & 32) ? r[0] : r[1]);
#else
        return __shfl_xor(v, 32, 64);
#endif
    }
}
template<int M>
__device__ __forceinline__ c32 cx(c32 v, int tid) {
    return (c32){lanex<M>(v.x, tid), lanex<M>(v.y, tid)};
}

template<int P>
__device__ __forceinline__ void gate_reg(c32* v, const c32* u) {
    const cg g00 = mkg(u[0]), g01 = mkg(u[1]), g10 = mkg(u[2]), g11 = mkg(u[3]);
    #pragma unroll
    for (int r = 0; r < R; ++r)
        if (!(r & (1 << P))) {
            c32 a = v[r], b = v[r | (1 << P)];
            v[r]            = cmadg(g01, b, cmulg(g00, a));
            v[r | (1 << P)] = cmadg(g11, b, cmulg(g10, a));
        }
}

template<int M>
__device__ __forceinline__ void gate_lane(c32* v, int tid, const c32* u) {
    const bool hi = tid & M;
    const c32 Ud = hi ? u[3] : u[0];
    const c32 Uo = hi ? u[2] : u[1];
    const cg gd = mkg(Ud), go = mkg(Uo);
    #pragma unroll
    for (int r = 0; r < R; ++r) {
        c32 o = cx<M>(v[r], tid);
        v[r] = cmadg(gd, v[r], cmulg(go, o));
    }
}

// exec-masked CNOT (partner lane shares the control bit; DPP reads src VGPRs
// regardless of EXEC) — verified R9.
template<int CM, int TM>
__device__ __forceinline__ void cnot_ll(c32* v, int tid) {
    if (tid & CM) {
        #pragma unroll
        for (int r = 0; r < R; ++r) v[r] = cx<TM>(v[r], tid);
    }
}

template<int PC, int PT>
__device__ __forceinline__ void cnot_rr(c32* v) {
    #pragma unroll
    for (int r = 0; r < R; ++r)
        if ((r & (1 << PC)) && !(r & (1 << PT))) {
            c32 t = v[r]; v[r] = v[r ^ (1 << PT)]; v[r ^ (1 << PT)] = t;
        }
}

__global__ __launch_bounds__(BLK, 1)
void qsim_kernel(const float* __restrict__ x,    // (B,12)
                 const float* __restrict__ w,    // (4,12,3)
                 const float* __restrict__ ent,  // (4,12)
                 float* __restrict__ out)        // (B,12)
{
    __shared__ c32  xbuf[NS];           // 32 KB cross-wave exchange
    __shared__ c32  gmat[NL * NQ][4];
    __shared__ c32  uenc[NQ][2];
    __shared__ unsigned long long emsh; // entangler bitmask
    __shared__ float redbuf[4 * NQ];

    const int tid = threadIdx.x;
    const int b   = blockIdx.x;

    bool f = false;
    if (tid < NL * NQ) {
        float phi = w[tid * 3 + 0], th = w[tid * 3 + 1], om = w[tid * 3 + 2];
        float s, c;   sincosf(0.5f * th, &s, &c);
        float sa, ca; sincosf(0.5f * (phi + om), &sa, &ca);
        float sm, cm; sincosf(0.5f * (phi - om), &sm, &cm);
        gmat[tid][0] = (c32){ c * ca, -c * sa};
        gmat[tid][1] = (c32){-s * cm, -s * sm};
        gmat[tid][2] = (c32){ s * cm, -s * sm};
        gmat[tid][3] = (c32){ c * ca,  c * sa};
        f = ent[tid] > 0.5f;
    }
    if (tid < 64) {                    // wave 0: build the 48-bit entangler mask
        unsigned long long m = __ballot(f);
        if (tid == 0) emsh = m;
    }
    if (tid >= 64 && tid < 64 + NQ) {
        int q = tid - 64;
        float xv = x[b * NQ + q];
        float s, c;   sincosf(0.5f * PI_F * xv, &s, &c);
        float zs, zc; sincosf(0.5f * PI_F * xv * xv, &zs, &zc);
        uenc[q][0] = (c32){c * zc, -c * zs};
        uenc[q][1] = (c32){s * zc,  s * zs};
    }
    __syncthreads();

    // entangler mask -> SGPR (uniform; scalar branches thereafter)
    const unsigned long long emv = emsh;
    const unsigned em_lo = __builtin_amdgcn_readfirstlane((unsigned)emv);
    const unsigned em_hi = __builtin_amdgcn_readfirstlane((unsigned)(emv >> 32));
    const unsigned long long em = (((unsigned long long)em_hi) << 32) | em_lo;
    #define ENT(i) ((em >> (i)) & 1ull)

    // ---- build encoded product state directly in registers ----
    c32 A = uenc[0][(tid >> 7) & 1];
    #pragma unroll
    for (int q = 1; q < 8; ++q) A = cmul(A, uenc[q][(tid >> (7 - q)) & 1]);
    c32 AP[4], PAB[4];
    #pragma unroll
    for (int j = 0; j < 4; ++j)
        AP[j] = cmul(A, cmul(uenc[8][j >> 1], uenc[9][j & 1]));
    #pragma unroll
    for (int k = 0; k < 4; ++k)
        PAB[k] = cmul(uenc[10][k >> 1], uenc[11][k & 1]);
    c32 v[R];
    #pragma unroll
    for (int r = 0; r < R; ++r) v[r] = cmul(AP[(r >> 2) & 3], PAB[r & 3]);

    const int lane_slot = tid & 63;
    const int g         = tid >> 6;   // quadrant = amp bits (11,10)

    // ---- layers ----
    #pragma unroll 1
    for (int layer = 0; layer < NL; ++layer) {
        const int gb = layer * NQ;

        // ===== batch-preload this layer's 12 gate matrices into registers =====
        // One pipelined ds_read burst + single waitcnt instead of 22 exposed
        // per-gate LDS latencies on the serial gate chain.
        c32 lc[12 * 4];
        #pragma unroll
        for (int k = 0; k < 12; ++k) {
            lc[4 * k + 0] = gmat[gb + k][0];
            lc[4 * k + 1] = gmat[gb + k][1];
            lc[4 * k + 2] = gmat[gb + k][2];
            lc[4 * k + 3] = gmat[gb + k][3];
        }

        // ===== fused 4x4 gate on amp bits (11,10) =====
        //   = Rot(bit11) ⊗ Rot(bit10), + this layer's CNOT(11,10) as row perm
        //   + prev layer's CNOT(0,11) as col perm on odd-r amplitudes.
        {
            #pragma unroll
            for (int r = 0; r < R; ++r) xbuf[r * BLK + tid] = v[r];

            const c32* Ua = lc + 0;
            const c32* Ub = lc + 4;
            const int  gp = (ENT(gb + 0) && (g & 2)) ? (g ^ 1) : g;  // CNOT(11,10) fold
            const int  ar = (gp >> 1) * 2, br = (gp & 1) * 2;
            c32 rowE[4];
            rowE[0] = cmul(Ua[ar + 0], Ub[br + 0]);
            rowE[1] = cmul(Ua[ar + 0], Ub[br + 1]);
            rowE[2] = cmul(Ua[ar + 1], Ub[br + 0]);
            rowE[3] = cmul(Ua[ar + 1], Ub[br + 1]);
            const bool pf = (layer > 0) && ENT(gb - 1);              // prev CNOT(0,11) fold
            cg gE[4], gO[4];
            #pragma unroll
            for (int j = 0; j < 4; ++j) {
                gE[j] = mkg(rowE[j]);
                gO[j] = mkg(pf ? rowE[j ^ 2] : rowE[j]);
            }

            __syncthreads();
            #pragma unroll
            for (int r = 0; r < R; ++r) {
                const cg* rw = (r & 1) ? gO : gE;
                c32 acc = cmulg(rw[0], xbuf[r * BLK +   0 + lane_slot]);
                acc     = cmadg(rw[1], xbuf[r * BLK +  64 + lane_slot], acc);
                acc     = cmadg(rw[2], xbuf[r * BLK + 128 + lane_slot], acc);
                acc     = cmadg(rw[3], xbuf[r * BLK + 192 + lane_slot], acc);
                v[r] = acc;
            }
            __syncthreads();
        }

        // ===== Rot gates on lane bits and reg bits (register coefficients) =====
        gate_lane<32>(v, tid, lc + 2  * 4);
        gate_lane<16>(v, tid, lc + 3  * 4);
        gate_lane< 8>(v, tid, lc + 4  * 4);
        gate_lane< 4>(v, tid, lc + 5  * 4);
        gate_lane< 2>(v, tid, lc + 6  * 4);
        gate_lane< 1>(v, tid, lc + 7  * 4);
        gate_reg<3>(v, lc + 8  * 4);
        gate_reg<2>(v, lc + 9  * 4);
        gate_reg<1>(v, lc + 10 * 4);
        gate_reg<0>(v, lc + 11 * 4);

        // ===== CNOT chain (q=0 folded above; q=11 folded forward) =====
        if (ENT(gb + 1) && (tid & 64)) {       // (10,9): ctrl wave bit6, tgt lane bit5
            #pragma unroll
            for (int r = 0; r < R; ++r) v[r] = cx<32>(v[r], tid);
        }
        if (ENT(gb + 2)) cnot_ll<32, 16>(v, tid);   // (9,8)
        if (ENT(gb + 3)) cnot_ll<16,  8>(v, tid);   // (8,7)
        if (ENT(gb + 4)) cnot_ll< 8,  4>(v, tid);   // (7,6)
        if (ENT(gb + 5)) cnot_ll< 4,  2>(v, tid);   // (6,5)
        if (ENT(gb + 6)) cnot_ll< 2,  1>(v, tid);   // (5,4)
        if (ENT(gb + 7)) {                          // (4,3): ctrl lane bit0, tgt reg bit3
            const bool c_ = tid & 1;
            #pragma unroll
            for (int r = 0; r < 8; ++r) {
                c32 a = v[r], bb = v[r | 8];
                v[r]     = c_ ? bb : a;
                v[r | 8] = c_ ? a  : bb;
            }
        }
        if (ENT(gb + 8))  cnot_rr<3, 2>(v);         // (3,2)
        if (ENT(gb + 9))  cnot_rr<2, 1>(v);         // (2,1)
        if (ENT(gb + 10)) cnot_rr<1, 0>(v);         // (1,0)
        // q=11 CNOT(0,11): folded into next fused gate, or into measurement
    }

    // ---- measurement; last layer's CNOT(0,11) folded into q0's sign ----
    const bool e011L = ENT((NL - 1) * NQ + 11);
    const int  t7    = (tid >> 7) & 1;

    float pr[R];
    #pragma unroll
    for (int r = 0; r < R; ++r) {
        c32 p = v[r] * v[r];
        pr[r] = p.x + p.y;
    }
    float S = 0.f, acc0 = 0.f;
    #pragma unroll
    for (int r = 0; r < R; ++r) {
        S += pr[r];
        const int s11 = t7 ^ (e011L & (r & 1));
        acc0 += s11 ? -pr[r] : pr[r];
    }
    float T[4];
    #pragma unroll
    for (int pb = 0; pb < 4; ++pb) {
        float t = 0.f;
        #pragma unroll
        for (int r = 0; r < R; ++r) t += ((r >> pb) & 1) ? -pr[r] : pr[r];
        T[pb] = t;
    }

    float contrib[NQ];
    contrib[0] = acc0;
    #pragma unroll
    for (int q = 1; q < 8; ++q) contrib[q] = ((tid >> (7 - q)) & 1) ? -S : S;
    contrib[8] = T[3]; contrib[9] = T[2]; contrib[10] = T[1]; contrib[11] = T[0];

    // all-VALU wave reduction (DPP/permlane)
    #pragma unroll
    for (int q = 0; q < NQ; ++q) {
        contrib[q] += lanex< 1>(contrib[q], tid);
        contrib[q] += lanex< 2>(contrib[q], tid);
        contrib[q] += lanex< 4>(contrib[q], tid);
        contrib[q] += lanex< 8>(contrib[q], tid);
        contrib[q] += lanex<16>(contrib[q], tid);
        contrib[q] += lanex<32>(contrib[q], tid);
    }
    if ((tid & 63) == 0) {
        const int wv = tid >> 6;
        #pragma unroll
        for (int q = 0; q < NQ; ++q) redbuf[wv * NQ + q] = contrib[q];
    }
    __syncthreads();
    if (tid < NQ)
        out[b * NQ + tid] = redbuf[tid] + redbuf[NQ + tid] + redbuf[2 * NQ + tid] + redbuf[3 * NQ + tid];
    #undef ENT
}

extern "C" void kernel_launch(void* const* d_in, const int* in_sizes, int n_in,
                              void* d_out, int out_size, void* d_ws, size_t ws_size,
                              hipStream_t stream) {
    const float* x   = (const float*)d_in[0];  // (B,12)
    const float* w   = (const float*)d_in[1];  // (4,12,3)
    const float* ent = (const float*)d_in[2];  // (4,12)
    float* out = (float*)d_out;
    const int B = in_sizes[0] / NQ;
    qsim_kernel<<<B, BLK, 0, stream>>>(x, w, ent, out);
}

// Round 12
// 88.433 us; speedup vs baseline: 1.0066x; 1.0066x over previous
//
#include <hip/hip_runtime.h>
#include <math.h>

constexpr int NQ  = 12;
constexpr int NS  = 1 << NQ;   // 4096 amplitudes
constexpr int NL  = 4;
constexpr int SB  = 256;       // threads per sample group
constexpr int BLK = 512;       // 2 samples per block -> 2 waves/SIMD
constexpr int R   = 16;        // amplitudes per thread (reg bits = amp bits 0..3)
constexpr float PI_F = 3.14159265358979323846f;

// within a sample group (stid = tid & 255):
// amp index i = (stid << 4) | r
//   bits 0..3  : register index r
//   bits 4..9  : lane bits (stid bits 0..5)
//   bits 10..11: group-wave bits (stid bits 6..7)

typedef float c32 __attribute__((ext_vector_type(2)));   // (re, im) -> v_pk_* math

__device__ __forceinline__ c32 cmul(c32 a, c32 b) {
    c32 t = (c32){-a.y, a.y} * b.yx;
    return (c32){a.x, a.x} * b + t;
}
struct cg { c32 xx, ny; };
__device__ __forceinline__ cg mkg(c32 u) {
    cg g; g.xx = (c32){u.x, u.x}; g.ny = (c32){-u.y, u.y}; return g;
}
__device__ __forceinline__ c32 cmulg(cg g, c32 b) { return g.xx * b + g.ny * b.yx; }
__device__ __forceinline__ c32 cmadg(cg g, c32 b, c32 c) { return g.xx * b + (g.ny * b.yx + c); }

// ---------------- VALU lane-exchange primitives ----------------
// row_shr:N = lane i <- i-N, row_shl:N = lane i <- i+N (verified R5).
template<int CTRL>
__device__ __forceinline__ float dppmov(float v) {
    return __int_as_float(__builtin_amdgcn_mov_dpp(__float_as_int(v), CTRL, 0xF, 0xF, false));
}
__device__ __forceinline__ float dppx4(float v) {
    int s = __float_as_int(v);
    int o = __builtin_amdgcn_update_dpp(s, s, 0x104, 0xF, 0x5, false); // row_shl:4 -> banks 0,2
    o     = __builtin_amdgcn_update_dpp(o, s, 0x114, 0xF, 0xA, false); // row_shr:4 -> banks 1,3
    return __int_as_float(o);
}

#if __has_builtin(__builtin_amdgcn_permlane16_swap)
#define HAVE_PL16 1
#endif
#if __has_builtin(__builtin_amdgcn_permlane32_swap)
#define HAVE_PL32 1
#endif

template<int M>
__device__ __forceinline__ float lanex(float v, int lid) {
    if constexpr (M == 1)  return dppmov<0xB1>(v);        // quad_perm [1,0,3,2]
    else if constexpr (M == 2)  return dppmov<0x4E>(v);   // quad_perm [2,3,0,1]
    else if constexpr (M == 4)  return dppx4(v);
    else if constexpr (M == 8)  return dppmov<0x128>(v);  // row_ror:8
    else if constexpr (M == 16) {
#ifdef HAVE_PL16
        auto r = __builtin_amdgcn_permlane16_swap(__float_as_int(v), __float_as_int(v), false, false);
        return __int_as_float((lid & 16) ? r[0] : r[1]);
#else
        return __shfl_xor(v, 16, 64);
#endif
    } else { // M == 32
#ifdef HAVE_PL32
        auto r = __builtin_amdgcn_permlane32_swap(__float_as_int(v), __float_as_int(v), false, false);
        return __int_as_float((lid & 32) ? r[0] : r[1]);
#else
        return __shfl_xor(v, 32, 64);
#endif
    }
}
template<int M>
__device__ __forceinline__ c32 cx(c32 v, int lid) {
    return (c32){lanex<M>(v.x, lid), lanex<M>(v.y, lid)};
}

template<int P>
__device__ __forceinline__ void gate_reg(c32* v, const c32* u) {
    const cg g00 = mkg(u[0]), g01 = mkg(u[1]), g10 = mkg(u[2]), g11 = mkg(u[3]);
    #pragma unroll
    for (int r = 0; r < R; ++r)
        if (!(r & (1 << P))) {
            c32 a = v[r], b = v[r | (1 << P)];
            v[r]            = cmadg(g01, b, cmulg(g00, a));
            v[r | (1 << P)] = cmadg(g11, b, cmulg(g10, a));
        }
}

template<int M>
__device__ __forceinline__ void gate_lane(c32* v, int stid, const c32* u) {
    const bool hi = stid & M;
    const c32 Ud = hi ? u[3] : u[0];
    const c32 Uo = hi ? u[2] : u[1];
    const cg gd = mkg(Ud), go = mkg(Uo);
    #pragma unroll
    for (int r = 0; r < R; ++r) {
        c32 o = cx<M>(v[r], stid);
        v[r] = cmadg(gd, v[r], cmulg(go, o));
    }
}

// exec-masked CNOT (partner lane shares the control bit; DPP reads src VGPRs
// regardless of EXEC) — verified R9.
template<int CM, int TM>
__device__ __forceinline__ void cnot_ll(c32* v, int stid) {
    if (stid & CM) {
        #pragma unroll
        for (int r = 0; r < R; ++r) v[r] = cx<TM>(v[r], stid);
    }
}

template<int PC, int PT>
__device__ __forceinline__ void cnot_rr(c32* v) {
    #pragma unroll
    for (int r = 0; r < R; ++r)
        if ((r & (1 << PC)) && !(r & (1 << PT))) {
            c32 t = v[r]; v[r] = v[r ^ (1 << PT)]; v[r ^ (1 << PT)] = t;
        }
}

__global__ __launch_bounds__(BLK, 1)
void qsim_kernel(const float* __restrict__ x,    // (B,12)
                 const float* __restrict__ w,    // (4,12,3)
                 const float* __restrict__ ent,  // (4,12)
                 float* __restrict__ out)        // (B,12)
{
    __shared__ c32  xbuf[2 * NS];       // 64 KB: per-sample cross-wave exchange
    __shared__ c32  gmat[NL * NQ][4];
    __shared__ c32  uenc[2][NQ][2];
    __shared__ unsigned long long emsh;
    __shared__ float redbuf[8 * NQ];

    const int tid  = threadIdx.x;
    const int s    = tid >> 8;          // sample slot within block
    const int stid = tid & (SB - 1);    // thread id within sample group
    const int b    = blockIdx.x * 2 + s;

    bool f = false;
    if (tid < NL * NQ) {
        float phi = w[tid * 3 + 0], th = w[tid * 3 + 1], om = w[tid * 3 + 2];
        float si, c;  sincosf(0.5f * th, &si, &c);
        float sa, ca; sincosf(0.5f * (phi + om), &sa, &ca);
        float sm, cm; sincosf(0.5f * (phi - om), &sm, &cm);
        gmat[tid][0] = (c32){ c  * ca, -c  * sa};
        gmat[tid][1] = (c32){-si * cm, -si * sm};
        gmat[tid][2] = (c32){ si * cm, -si * sm};
        gmat[tid][3] = (c32){ c  * ca,  c  * sa};
        f = ent[tid] > 0.5f;
    }
    if (tid < 64) {                    // wave 0: 48-bit entangler mask
        unsigned long long m = __ballot(f);
        if (tid == 0) emsh = m;
    }
    if (stid >= 64 && stid < 64 + NQ) {  // each sample group fills its uenc
        int q = stid - 64;
        float xv = x[b * NQ + q];
        float si, c;  sincosf(0.5f * PI_F * xv, &si, &c);
        float zs, zc; sincosf(0.5f * PI_F * xv * xv, &zs, &zc);
        uenc[s][q][0] = (c32){c  * zc, -c  * zs};
        uenc[s][q][1] = (c32){si * zc,  si * zs};
    }
    __syncthreads();

    const unsigned long long emv = emsh;
    const unsigned em_lo = __builtin_amdgcn_readfirstlane((unsigned)emv);
    const unsigned em_hi = __builtin_amdgcn_readfirstlane((unsigned)(emv >> 32));
    const unsigned long long em = (((unsigned long long)em_hi) << 32) | em_lo;
    #define ENT(i) ((em >> (i)) & 1ull)

    // ---- build encoded product state directly in registers ----
    const c32 (*ue)[2] = uenc[s];
    c32 A = ue[0][(stid >> 7) & 1];
    #pragma unroll
    for (int q = 1; q < 8; ++q) A = cmul(A, ue[q][(stid >> (7 - q)) & 1]);
    c32 AP[4], PAB[4];
    #pragma unroll
    for (int j = 0; j < 4; ++j)
        AP[j] = cmul(A, cmul(ue[8][j >> 1], ue[9][j & 1]));
    #pragma unroll
    for (int k = 0; k < 4; ++k)
        PAB[k] = cmul(ue[10][k >> 1], ue[11][k & 1]);
    c32 v[R];
    #pragma unroll
    for (int r = 0; r < R; ++r) v[r] = cmul(AP[(r >> 2) & 3], PAB[r & 3]);

    const int lane_slot = stid & 63;
    const int g         = stid >> 6;    // quadrant = amp bits (11,10)
    c32* xb = xbuf + s * NS;

    // ---- layers ----
    #pragma unroll 1
    for (int layer = 0; layer < NL; ++layer) {
        const int gb = layer * NQ;

        // ===== fused 4x4 gate on amp bits (11,10) =====
        //   = Rot(bit11) ⊗ Rot(bit10), + this layer's CNOT(11,10) as row perm
        //   + prev layer's CNOT(0,11) as col perm on odd-r amplitudes.
        {
            #pragma unroll
            for (int r = 0; r < R; ++r) xb[r * SB + stid] = v[r];

            const c32* Ua = gmat[gb + 0];
            const c32* Ub = gmat[gb + 1];
            const int  gp = (ENT(gb + 0) && (g & 2)) ? (g ^ 1) : g;  // CNOT(11,10) fold
            const int  ar = (gp >> 1) * 2, br = (gp & 1) * 2;
            c32 rowE[4];
            rowE[0] = cmul(Ua[ar + 0], Ub[br + 0]);
            rowE[1] = cmul(Ua[ar + 0], Ub[br + 1]);
            rowE[2] = cmul(Ua[ar + 1], Ub[br + 0]);
            rowE[3] = cmul(Ua[ar + 1], Ub[br + 1]);
            const bool pf = (layer > 0) && ENT(gb - 1);              // prev CNOT(0,11) fold
            cg gE[4], gO[4];
            #pragma unroll
            for (int j = 0; j < 4; ++j) {
                gE[j] = mkg(rowE[j]);
                gO[j] = mkg(pf ? rowE[j ^ 2] : rowE[j]);
            }

            __syncthreads();
            #pragma unroll
            for (int r = 0; r < R; ++r) {
                const cg* rw = (r & 1) ? gO : gE;
                c32 acc = cmulg(rw[0], xb[r * SB +   0 + lane_slot]);
                acc     = cmadg(rw[1], xb[r * SB +  64 + lane_slot], acc);
                acc     = cmadg(rw[2], xb[r * SB + 128 + lane_slot], acc);
                acc     = cmadg(rw[3], xb[r * SB + 192 + lane_slot], acc);
                v[r] = acc;
            }
            __syncthreads();
        }

        // ===== Rot gates on lane bits and reg bits =====
        gate_lane<32>(v, stid, gmat[gb + 2]);
        gate_lane<16>(v, stid, gmat[gb + 3]);
        gate_lane< 8>(v, stid, gmat[gb + 4]);
        gate_lane< 4>(v, stid, gmat[gb + 5]);
        gate_lane< 2>(v, stid, gmat[gb + 6]);
        gate_lane< 1>(v, stid, gmat[gb + 7]);
        gate_reg<3>(v, gmat[gb + 8]);
        gate_reg<2>(v, gmat[gb + 9]);
        gate_reg<1>(v, gmat[gb + 10]);
        gate_reg<0>(v, gmat[gb + 11]);

        // ===== CNOT chain (q=0 folded above; q=11 folded forward) =====
        if (ENT(gb + 1) && (stid & 64)) {      // (10,9): ctrl group-wave bit6, tgt lane bit5
            #pragma unroll
            for (int r = 0; r < R; ++r) v[r] = cx<32>(v[r], stid);
        }
        if (ENT(gb + 2)) cnot_ll<32, 16>(v, stid);   // (9,8)
        if (ENT(gb + 3)) cnot_ll<16,  8>(v, stid);   // (8,7)
        if (ENT(gb + 4)) cnot_ll< 8,  4>(v, stid);   // (7,6)
        if (ENT(gb + 5)) cnot_ll< 4,  2>(v, stid);   // (6,5)
        if (ENT(gb + 6)) cnot_ll< 2,  1>(v, stid);   // (5,4)
        if (ENT(gb + 7)) {                           // (4,3): ctrl lane bit0, tgt reg bit3
            const bool c_ = stid & 1;
            #pragma unroll
            for (int r = 0; r < 8; ++r) {
                c32 a = v[r], bb = v[r | 8];
                v[r]     = c_ ? bb : a;
                v[r | 8] = c_ ? a  : bb;
            }
        }
        if (ENT(gb + 8))  cnot_rr<3, 2>(v);          // (3,2)
        if (ENT(gb + 9))  cnot_rr<2, 1>(v);          // (2,1)
        if (ENT(gb + 10)) cnot_rr<1, 0>(v);          // (1,0)
        // q=11 CNOT(0,11): folded into next fused gate, or into measurement
    }

    // ---- measurement; last layer's CNOT(0,11) folded into q0's sign ----
    const bool e011L = ENT((NL - 1) * NQ + 11);
    const int  t7    = (stid >> 7) & 1;

    float pr[R];
    #pragma unroll
    for (int r = 0; r < R; ++r) {
        c32 p = v[r] * v[r];
        pr[r] = p.x + p.y;
    }
    float S = 0.f, acc0 = 0.f;
    #pragma unroll
    for (int r = 0; r < R; ++r) {
        S += pr[r];
        const int s11 = t7 ^ (e011L & (r & 1));
        acc0 += s11 ? -pr[r] : pr[r];
    }
    float T[4];
    #pragma unroll
    for (int pb = 0; pb < 4; ++pb) {
        float t = 0.f;
        #pragma unroll
        for (int r = 0; r < R; ++r) t += ((r >> pb) & 1) ? -pr[r] : pr[r];
        T[pb] = t;
    }

    float contrib[NQ];
    contrib[0] = acc0;
    #pragma unroll
    for (int q = 1; q < 8; ++q) contrib[q] = ((stid >> (7 - q)) & 1) ? -S : S;
    contrib[8] = T[3]; contrib[9] = T[2]; contrib[10] = T[1]; contrib[11] = T[0];

    // all-VALU wave reduction (DPP/permlane)
    #pragma unroll
    for (int q = 0; q < NQ; ++q) {
        contrib[q] += lanex< 1>(contrib[q], stid);
        contrib[q] += lanex< 2>(contrib[q], stid);
        contrib[q] += lanex< 4>(contrib[q], stid);
        contrib[q] += lanex< 8>(contrib[q], stid);
        contrib[q] += lanex<16>(contrib[q], stid);
        contrib[q] += lanex<32>(contrib[q], stid);
    }
    if ((tid & 63) == 0) {
        const int wv = tid >> 6;    // 0..7 across the block
        #pragma unroll
        for (int q = 0; q < NQ; ++q) redbuf[wv * NQ + q] = contrib[q];
    }
    __syncthreads();
    if (stid < NQ) {
        const float* rb = redbuf + s * 4 * NQ;
        out[b * NQ + stid] = rb[stid] + rb[NQ + stid] + rb[2 * NQ + stid] + rb[3 * NQ + stid];
    }
    #undef ENT
}

extern "C" void kernel_launch(void* const* d_in, const int* in_sizes, int n_in,
                              void* d_out, int out_size, void* d_ws, size_t ws_size,
                              hipStream_t stream) {
    const float* x   = (const float*)d_in[0];  // (B,12)
    const float* w   = (const float*)d_in[1];  // (4,12,3)
    const float* ent = (const float*)d_in[2];  // (4,12)
    float* out = (float*)d_out;
    const int B = in_sizes[0] / NQ;
    qsim_kernel<<<B / 2, BLK, 0, stream>>>(x, w, ent, out);
}